// Round 7
// baseline (465.008 us; speedup 1.0000x reference)
//
#include <hip/hip_runtime.h>
#include <hip/hip_bf16.h>
#include <cmath>

#define NT 4096      // B*S tokens
#define HD 768
#define ID 3072
#define NE 7
#define NP 8192      // NT * TOP_K
#define TM 256
#define TN 256
#define BK 32        // 4 chunks of 8 bf16 per row per K-tile
#define KS 2         // split-K factor for ffn2
#define NT2 (HD / TN)   // 3 n-tiles in ffn2
#define SLOTS 102    // worst-case tiles per XCD in ffn2 ((32+2)*3)
#define NRING 4      // LDS ring depth (stage 3 tiles ahead)
#define FFN1_MT 39   // worst-case sum of ceil(cnt/256) = 32 + 7
#define FFN1_NT (ID / TN)          // 12 n-tiles
#define FFN1_GRID (FFN1_NT * FFN1_MT)   // 468

// prep_kernel grid sections
#define G_GATE 1024              // 4 tokens (1 per wave) per 256-thread block
#define G_TR1  (48 * 12 * NE)    // w1 transpose tiles (N=ID/64 x K=HD/64 x E)
#define G_TR2  (12 * 48 * NE)    // w2 transpose tiles (N=HD/64 x K=ID/64 x E)

using short8 = __attribute__((ext_vector_type(8))) short;
using f32x4  = __attribute__((ext_vector_type(4))) float;
typedef __hip_bfloat16 bf16;

// async global->LDS, 16B per lane, wave-uniform base + lane*16
typedef const __attribute__((address_space(1))) void* gas_ptr;
typedef __attribute__((address_space(3))) void* las_ptr;
#define GLDS(g, l) __builtin_amdgcn_global_load_lds((gas_ptr)(g), (las_ptr)(l), 16, 0, 0)

#define BAR()   asm volatile("s_barrier" ::: "memory")
#define WAITL() asm volatile("s_waitcnt lgkmcnt(0)" ::: "memory")
#define WV8()   asm volatile("s_waitcnt vmcnt(8)" ::: "memory")
#define WV4()   asm volatile("s_waitcnt vmcnt(4)" ::: "memory")
#define WV0()   asm volatile("s_waitcnt vmcnt(0)" ::: "memory")
#define SCHEDB() __builtin_amdgcn_sched_barrier(0)

__device__ inline float b2f(unsigned short u) {
  unsigned v = (unsigned)u << 16; float f; __builtin_memcpy(&f, &v, 4); return f;
}

// exact-erf GELU via A&S 7.1.26 rational (|err| <= 1.5e-7, branch-free, v_exp/v_rcp)
__device__ inline float gelu_erf(float v) {
  float xa = fabsf(v) * 0.70710678118654752f;
  float t  = __builtin_amdgcn_rcpf(1.0f + 0.3275911f * xa);
  float p  = t * (0.254829592f + t * (-0.284496736f + t * (1.421413741f +
             t * (-1.453152027f + t * 1.061405429f))));
  float er = 1.0f - p * __expf(-xa * xa);
  er = (v < 0.0f) ? -er : er;
  return 0.5f * v * (1.0f + er);
}

// ---------------- fp32 [K][N] -> bf16 [N][K] 64x64 transpose tile (shared body) ----------
__device__ inline void transpose_body(const float* __restrict__ s, bf16* __restrict__ d,
                                      int K, int N, int n0, int k0, int t,
                                      float (*tile)[65]) {
  {
    int kk = t >> 4;            // 0..15
    int nc = (t & 15) << 2;     // 0,4,...,60
#pragma unroll
    for (int r = 0; r < 4; r++) {
      int k = kk + r * 16;
      float4 v = *(const float4*)(s + (size_t)(k0 + k) * N + n0 + nc);
      tile[k][nc + 0] = v.x; tile[k][nc + 1] = v.y;
      tile[k][nc + 2] = v.z; tile[k][nc + 3] = v.w;
    }
  }
  __syncthreads();
  {
    int c = t & 15;             // k-chunk (4 elems)
    int nbase = t >> 4;         // 0..15
#pragma unroll
    for (int r = 0; r < 4; r++) {
      int n = nbase + r * 16;
      bf16 tmp[4];
#pragma unroll
      for (int i = 0; i < 4; i++) tmp[i] = __float2bfloat16(tile[4 * c + i][n]);
      ushort4 u; __builtin_memcpy(&u, tmp, 8);
      *(ushort4*)(d + (size_t)(n0 + n) * K + k0 + 4 * c) = u;
    }
  }
}

// ---------------- prep: gate (+x->bf16 +out zero) || w1 transpose || w2 transpose --------
// Sections by blockIdx.x; fully data-independent -> one launch replaces three and the
// three memory streams overlap instead of serializing across launch gaps.
__global__ __launch_bounds__(256) void prep_kernel(
    const float* __restrict__ x, const float* __restrict__ wg, const float* __restrict__ bg,
    const float* __restrict__ w1, const float* __restrict__ w2,
    float* __restrict__ gate_out, float* __restrict__ out, bf16* __restrict__ xb,
    float* __restrict__ pair_w, int* __restrict__ tokexp,
    bf16* __restrict__ w1t, bf16* __restrict__ w2t)
{
  __shared__ float tile[64][65];
  int b = blockIdx.x;
  int tid = threadIdx.x;

  if (b < G_GATE) {
    // ---- gate section: 4 tokens per block, one per wave ----
    int wavei = tid >> 6, lane = tid & 63;
    int t = b * 4 + wavei;
    const float* xr = x + (size_t)t * HD;
    float acc[NE];
#pragma unroll
    for (int e = 0; e < NE; e++) acc[e] = 0.f;
#pragma unroll
    for (int j = 0; j < HD / 64; j++) {
      int h = lane + j * 64;
      float xv = xr[h];
      xb[(size_t)t * HD + h] = __float2bfloat16(xv);
      const float* wr = wg + (size_t)h * NE;
#pragma unroll
      for (int e = 0; e < NE; e++) acc[e] += xv * wr[e];
    }
    // zero the fp32 output row (ffn2 accumulates into it atomically)
    f32x4 z = {0.f, 0.f, 0.f, 0.f};
#pragma unroll
    for (int jj = 0; jj < 3; jj++)
      ((f32x4*)(out + (size_t)t * HD))[lane + jj * 64] = z;
#pragma unroll
    for (int e = 0; e < NE; e++) {
      float v = acc[e];
      for (int s = 32; s > 0; s >>= 1) v += __shfl_down(v, s, 64);
      acc[e] = v;
    }
    if (lane == 0) {
      float lg[NE];
#pragma unroll
      for (int e = 0; e < NE; e++) lg[e] = acc[e] + bg[e];
      int i0 = 0;
      for (int e = 1; e < NE; e++) if (lg[e] > lg[i0]) i0 = e;  // first index wins ties
      int i1 = -1;
      for (int e = 0; e < NE; e++) {
        if (e == i0) continue;
        if (i1 < 0 || lg[e] > lg[i1]) i1 = e;
      }
      float v0 = lg[i0], v1 = lg[i1];
      float e1 = expf(v1 - v0);
      float inv = 1.f / (1.f + e1);
      float w0 = inv, w1v = e1 * inv;
      float* go = gate_out + (size_t)t * NE;
#pragma unroll
      for (int e = 0; e < NE; e++) go[e] = 0.f;
      go[i0] = w0; go[i1] = w1v;
      pair_w[2 * t + 0] = w0;
      pair_w[2 * t + 1] = w1v;
      tokexp[2 * t + 0] = i0;
      tokexp[2 * t + 1] = i1;
    }
  } else if (b < G_GATE + G_TR1) {
    // ---- w1 transpose: [HD][ID] fp32 -> [ID][HD] bf16 per expert ----
    int id = b - G_GATE;
    int e = id / (48 * 12);
    int rem = id % (48 * 12);
    int bx = rem % 48, by = rem / 48;        // bx: n-tile (ID), by: k-tile (HD)
    transpose_body(w1 + (size_t)e * HD * ID, w1t + (size_t)e * HD * ID,
                   HD, ID, bx * 64, by * 64, tid, tile);
  } else {
    // ---- w2 transpose: [ID][HD] fp32 -> [HD][ID] bf16 per expert ----
    int id = b - G_GATE - G_TR1;
    int e = id / (12 * 48);
    int rem = id % (12 * 48);
    int bx = rem % 12, by = rem / 12;        // bx: n-tile (HD), by: k-tile (ID)
    transpose_body(w2 + (size_t)e * ID * HD, w2t + (size_t)e * ID * HD,
                   ID, HD, bx * 64, by * 64, tid, tile);
  }
}

// ---------------- routing: deterministic compaction, one block per expert ----------------
__global__ __launch_bounds__(256) void route_kernel(
    const int* __restrict__ tokexp, int* __restrict__ elist, int* __restrict__ counts)
{
  __shared__ int wcnt[4];
  int e = blockIdx.x;
  int tid = threadIdx.x, wv = tid >> 6, ln = tid & 63;
  int base = 0;
  for (int chunk = 0; chunk < NP; chunk += 256) {
    int p = chunk + tid;
    bool m = (tokexp[p] == e);
    unsigned long long bal = __ballot(m);
    if (ln == 0) wcnt[wv] = __popcll(bal);
    __syncthreads();
    int pre = 0;
#pragma unroll
    for (int w = 0; w < 4; w++) pre += (w < wv) ? wcnt[w] : 0;
    int rank = pre + __popcll(bal & ((1ull << ln) - 1ull));
    if (m) elist[e * NP + base + rank] = p;
    base += wcnt[0] + wcnt[1] + wcnt[2] + wcnt[3];
    __syncthreads();
  }
  if (tid == 0) counts[e] = base;
}

// ================= shared GEMM machinery (R4 schedule — best measured) =================
// 256x256 tile, 512 threads = 8 waves (2m x 4n), per-wave output 128x64, acc[8][4].
// LDS: ring of 4 K-tiles (BK=32): As/Bs[4][256][4][8] = 128 KB + plist -> 1 block/CU.
// Chunk-XOR layout (0 conflicts): phys slot p holds logical chunk kc = p ^ ((row>>1)&3);
// fragment read phys ph = quad ^ ((lr>>1)&3). Staging c0=tid (rows 0..127), c1=tid+512.
// Two phases per K-tile, 2 barriers each; counted vmcnt (8/4/0 tail) keeps 2-3 tiles
// in flight across barriers. MFMA operands SWAPPED (bfr, af) -> lane holds 4
// consecutive output cols -> 8 B vectorized epilogue stores.

// ---------------- grouped GEMM 1: h = gelu(x_g @ W1e + b1e), bf16 out ----------------
// Bijective XCD swizzle: nwg=468, q=58, r=4; xcd = raw%8 gets a contiguous n-fast run.
__global__ __launch_bounds__(512, 2) void ffn1_kernel(
    const bf16* __restrict__ xb, const bf16* __restrict__ w1t, const float* __restrict__ b1,
    const int* __restrict__ counts, const int* __restrict__ elist, bf16* __restrict__ hbuf)
{
  __shared__ bf16 As[NRING][TM][4][8];   // 64 KB
  __shared__ bf16 Bs[NRING][TN][4][8];   // 64 KB
  __shared__ int plist[TM];

  int tid = threadIdx.x;
  int raw = blockIdx.x;
  int xcd = raw & 7, pos = raw >> 3;
  int v = (xcd < 4) ? xcd * 59 + pos : 236 + (xcd - 4) * 58 + pos;
  int by = v / FFN1_NT, bx = v % FFN1_NT;

  int e, base = 0, cnt = 0, acct = 0;
  bool found = false;
  for (e = 0; e < NE; e++) {
    cnt = counts[e];
    int tiles = (cnt + TM - 1) / TM;
    if (by < acct + tiles) { base = (by - acct) * TM; found = true; break; }
    acct += tiles;
  }
  if (!found) return;

  if (tid < TM) {
    int r = base + tid;
    plist[tid] = (r < cnt) ? elist[e * NP + r] : -1;
  }
  __syncthreads();

  const int n0 = bx * TN;
  const bf16* Bsrc = w1t + (size_t)e * ID * HD;  // [ID][HD] bf16, K-contiguous

  int c0 = tid, c1 = tid + 512;
  int r0 = c0 >> 2, k0 = (c0 & 3) ^ ((r0 >> 1) & 3);
  int r1 = c1 >> 2, k1 = (c1 & 3) ^ ((r1 >> 1) & 3);
  int pr0 = plist[r0], pr1 = plist[r1];
  const bf16* a0 = xb + (size_t)((pr0 >= 0 ? pr0 : 0) >> 1) * HD + k0 * 8;
  const bf16* a1 = xb + (size_t)((pr1 >= 0 ? pr1 : 0) >> 1) * HD + k1 * 8;
  const bf16* b0 = Bsrc + (size_t)(n0 + r0) * HD + k0 * 8;
  const bf16* b1v = Bsrc + (size_t)(n0 + r1) * HD + k1 * 8;

#define STAGE_A(t_) do { bf16* d_ = (bf16*)As + (size_t)((t_) & 3) * TM * 32;    \
    GLDS(a0 + (size_t)(t_) * BK, d_ + c0 * 8);                                   \
    GLDS(a1 + (size_t)(t_) * BK, d_ + c1 * 8); } while (0)
#define STAGE_B(t_) do { bf16* d_ = (bf16*)Bs + (size_t)((t_) & 3) * TN * 32;    \
    GLDS(b0 + (size_t)(t_) * BK, d_ + c0 * 8);                                   \
    GLDS(b1v + (size_t)(t_) * BK, d_ + c1 * 8); } while (0)

  int wave = tid >> 6, lane = tid & 63;
  int wm = (wave >> 2) * 128, wn = (wave & 3) * 64;
  int lr = lane & 15, quad = lane >> 4;
  int ph = quad ^ ((lr >> 1) & 3);

  f32x4 acc[8][4] = {};
  const int NIT = HD / BK;  // 24

  STAGE_A(0); STAGE_B(0);
  STAGE_A(1); STAGE_B(1);
  STAGE_A(2); STAGE_B(2);
  WV8(); BAR();

  for (int t = 0; t < NIT; ++t) {
    int q = t & 3;
    short8 af[4], bfr[4];
    // ---- phase A: rows wm+0..63 ----
#pragma unroll
    for (int mi = 0; mi < 4; mi++) af[mi] = *(const short8*)&As[q][wm + mi * 16 + lr][ph][0];
#pragma unroll
    for (int nj = 0; nj < 4; nj++) bfr[nj] = *(const short8*)&Bs[q][wn + nj * 16 + lr][ph][0];
    if (t + 3 < NIT) STAGE_A(t + 3);
    BAR();
    WAITL(); SCHEDB();
    __builtin_amdgcn_s_setprio(1);
#pragma unroll
    for (int mi = 0; mi < 4; mi++)
#pragma unroll
      for (int nj = 0; nj < 4; nj++)
        acc[mi][nj] = __builtin_amdgcn_mfma_f32_16x16x32_bf16(bfr[nj], af[mi], acc[mi][nj], 0, 0, 0);
    __builtin_amdgcn_s_setprio(0);
    BAR();
    // ---- phase B: rows wm+64..127 ----
#pragma unroll
    for (int mi = 0; mi < 4; mi++) af[mi] = *(const short8*)&As[q][wm + 64 + mi * 16 + lr][ph][0];
    if (t + 3 < NIT) STAGE_B(t + 3);
    if (t + 3 < NIT) { WV8(); } else if (t + 2 < NIT) { WV4(); } else if (t + 1 < NIT) { WV0(); }
    BAR();
    WAITL(); SCHEDB();
    __builtin_amdgcn_s_setprio(1);
#pragma unroll
    for (int mi = 0; mi < 4; mi++)
#pragma unroll
      for (int nj = 0; nj < 4; nj++)
        acc[4 + mi][nj] = __builtin_amdgcn_mfma_f32_16x16x32_bf16(bfr[nj], af[mi], acc[4 + mi][nj], 0, 0, 0);
    __builtin_amdgcn_s_setprio(0);
    BAR();
  }
#undef STAGE_A
#undef STAGE_B

  // epilogue: lane holds 4 consecutive cols (n = n0+wn+nj*16+quad*4+r) of row
  // m = wm+mi*16+lr -> 8 B stores; nj inner completes each 128 B line fast.
  const float* b1e = b1 + (size_t)e * ID;
#pragma unroll
  for (int mi = 0; mi < 8; mi++) {
    int mrow = wm + mi * 16 + lr;
    int p = plist[mrow];
    if (p >= 0) {
      bf16* drow = hbuf + (size_t)p * ID;
#pragma unroll
      for (int nj = 0; nj < 4; nj++) {
        int colb = n0 + wn + nj * 16 + (quad << 2);
        float4 bs = *(const float4*)(b1e + colb);
        bf16 o[4];
        o[0] = __float2bfloat16(gelu_erf(acc[mi][nj][0] + bs.x));
        o[1] = __float2bfloat16(gelu_erf(acc[mi][nj][1] + bs.y));
        o[2] = __float2bfloat16(gelu_erf(acc[mi][nj][2] + bs.z));
        o[3] = __float2bfloat16(gelu_erf(acc[mi][nj][3] + bs.w));
        ushort4 u; __builtin_memcpy(&u, o, 8);
        *(ushort4*)(drow + colb) = u;
      }
    }
  }
}

// ---------------- grouped GEMM 2 (split-K, XCD-pinned), combine FUSED via atomicAdd ----
// pout round-trip + combine kernel eliminated: out[tok] += (acc + b2?) * pair_w, fp32
// device-scope atomics (4 adds per element: 2 experts x 2 k-segments; out zeroed in prep).
__global__ __launch_bounds__(512, 2) void ffn2_kernel(
    const bf16* __restrict__ hbuf, const bf16* __restrict__ w2t, const float* __restrict__ b2,
    const int* __restrict__ counts, const int* __restrict__ elist,
    const float* __restrict__ pair_w, float* __restrict__ out)
{
  __shared__ bf16 As[NRING][TM][4][8];
  __shared__ bf16 Bs[NRING][TN][4][8];
  __shared__ int plist[TM];

  int tid = threadIdx.x;
  int xcd = blockIdx.x;
  int slot = blockIdx.y;
  int e = 0, seg = 0, base = 0, cnt = 0, n0 = 0;
  bool found = false;
  for (int p = xcd; p < 2 * NE; p += 8) {
    int pe = p >> 1;
    int c = counts[pe];
    int tiles = ((c + TM - 1) / TM) * NT2;
    if (slot < tiles) {
      e = pe; seg = p & 1; cnt = c;
      base = (slot / NT2) * TM;
      n0 = (slot % NT2) * TN;
      found = true; break;
    }
    slot -= tiles;
  }
  if (!found) return;

  if (tid < TM) {
    int r = base + tid;
    plist[tid] = (r < cnt) ? elist[e * NP + r] : -1;
  }
  __syncthreads();

  const int kbase = seg * (ID / KS);
  const bf16* Bsrc = w2t + (size_t)e * HD * ID;  // [HD][ID] bf16, K-contiguous

  int c0 = tid, c1 = tid + 512;
  int r0 = c0 >> 2, k0 = (c0 & 3) ^ ((r0 >> 1) & 3);
  int r1 = c1 >> 2, k1 = (c1 & 3) ^ ((r1 >> 1) & 3);
  int pr0 = plist[r0], pr1 = plist[r1];
  const bf16* a0 = hbuf + (size_t)(pr0 >= 0 ? pr0 : 0) * ID + kbase + k0 * 8;
  const bf16* a1 = hbuf + (size_t)(pr1 >= 0 ? pr1 : 0) * ID + kbase + k1 * 8;
  const bf16* b0 = Bsrc + (size_t)(n0 + r0) * ID + kbase + k0 * 8;
  const bf16* b1v = Bsrc + (size_t)(n0 + r1) * ID + kbase + k1 * 8;

#define STAGE_A(t_) do { bf16* d_ = (bf16*)As + (size_t)((t_) & 3) * TM * 32;    \
    GLDS(a0 + (size_t)(t_) * BK, d_ + c0 * 8);                                   \
    GLDS(a1 + (size_t)(t_) * BK, d_ + c1 * 8); } while (0)
#define STAGE_B(t_) do { bf16* d_ = (bf16*)Bs + (size_t)((t_) & 3) * TN * 32;    \
    GLDS(b0 + (size_t)(t_) * BK, d_ + c0 * 8);                                   \
    GLDS(b1v + (size_t)(t_) * BK, d_ + c1 * 8); } while (0)

  int wave = tid >> 6, lane = tid & 63;
  int wm = (wave >> 2) * 128, wn = (wave & 3) * 64;
  int lr = lane & 15, quad = lane >> 4;
  int ph = quad ^ ((lr >> 1) & 3);

  f32x4 acc[8][4] = {};
  const int NIT = (ID / KS) / BK;  // 48

  STAGE_A(0); STAGE_B(0);
  STAGE_A(1); STAGE_B(1);
  STAGE_A(2); STAGE_B(2);
  WV8(); BAR();

  for (int t = 0; t < NIT; ++t) {
    int q = t & 3;
    short8 af[4], bfr[4];
    // ---- phase A ----
#pragma unroll
    for (int mi = 0; mi < 4; mi++) af[mi] = *(const short8*)&As[q][wm + mi * 16 + lr][ph][0];
#pragma unroll
    for (int nj = 0; nj < 4; nj++) bfr[nj] = *(const short8*)&Bs[q][wn + nj * 16 + lr][ph][0];
    if (t + 3 < NIT) STAGE_A(t + 3);
    BAR();
    WAITL(); SCHEDB();
    __builtin_amdgcn_s_setprio(1);
#pragma unroll
    for (int mi = 0; mi < 4; mi++)
#pragma unroll
      for (int nj = 0; nj < 4; nj++)
        acc[mi][nj] = __builtin_amdgcn_mfma_f32_16x16x32_bf16(bfr[nj], af[mi], acc[mi][nj], 0, 0, 0);
    __builtin_amdgcn_s_setprio(0);
    BAR();
    // ---- phase B ----
#pragma unroll
    for (int mi = 0; mi < 4; mi++) af[mi] = *(const short8*)&As[q][wm + 64 + mi * 16 + lr][ph][0];
    if (t + 3 < NIT) STAGE_B(t + 3);
    if (t + 3 < NIT) { WV8(); } else if (t + 2 < NIT) { WV4(); } else if (t + 1 < NIT) { WV0(); }
    BAR();
    WAITL(); SCHEDB();
    __builtin_amdgcn_s_setprio(1);
#pragma unroll
    for (int mi = 0; mi < 4; mi++)
#pragma unroll
      for (int nj = 0; nj < 4; nj++)
        acc[4 + mi][nj] = __builtin_amdgcn_mfma_f32_16x16x32_bf16(bfr[nj], af[mi], acc[4 + mi][nj], 0, 0, 0);
    __builtin_amdgcn_s_setprio(0);
    BAR();
  }
#undef STAGE_A
#undef STAGE_B

  // epilogue: fused combine — atomicAdd weighted fp32 rows into out[tok].
  const float* b2e = b2 + (size_t)e * HD;
#pragma unroll
  for (int mi = 0; mi < 8; mi++) {
    int mrow = wm + mi * 16 + lr;
    int p = plist[mrow];
    if (p >= 0) {
      float pw = pair_w[p];
      float* orow = out + (size_t)(p >> 1) * HD;
#pragma unroll
      for (int nj = 0; nj < 4; nj++) {
        int colb = n0 + wn + nj * 16 + (quad << 2);
        float bx_ = 0.f, by_ = 0.f, bz_ = 0.f, bw_ = 0.f;
        if (seg == 0) {
          float4 bs = *(const float4*)(b2e + colb);
          bx_ = bs.x; by_ = bs.y; bz_ = bs.z; bw_ = bs.w;
        }
        atomicAdd(&orow[colb + 0], (acc[mi][nj][0] + bx_) * pw);
        atomicAdd(&orow[colb + 1], (acc[mi][nj][1] + by_) * pw);
        atomicAdd(&orow[colb + 2], (acc[mi][nj][2] + bz_) * pw);
        atomicAdd(&orow[colb + 3], (acc[mi][nj][3] + bw_) * pw);
      }
    }
  }
}

extern "C" void kernel_launch(void* const* d_in, const int* in_sizes, int n_in,
                              void* d_out, int out_size, void* d_ws, size_t ws_size,
                              hipStream_t stream)
{
  const float* x  = (const float*)d_in[0];
  const float* wg = (const float*)d_in[1];
  const float* bg = (const float*)d_in[2];
  const float* w1 = (const float*)d_in[3];
  const float* b1 = (const float*)d_in[4];
  const float* w2 = (const float*)d_in[5];
  const float* b2 = (const float*)d_in[6];
  float* out = (float*)d_out;
  float* gate_out = out + (size_t)NT * HD;  // second output [B,S,E]

  // workspace layout (~96 MB total, 16B-aligned offsets)
  char* ws = (char*)d_ws;
  size_t off = 0;
  int* counts  = (int*)(ws + off);  off += 256;
  int* tokexp  = (int*)(ws + off);  off += (size_t)NP * 4;
  int* elist   = (int*)(ws + off);  off += (size_t)NE * NP * 4;
  float* pair_w = (float*)(ws + off); off += (size_t)NP * 4;
  bf16* xb   = (bf16*)(ws + off);   off += (size_t)NT * HD * 2;
  bf16* w1t  = (bf16*)(ws + off);   off += (size_t)NE * HD * ID * 2;
  bf16* w2t  = (bf16*)(ws + off);   off += (size_t)NE * HD * ID * 2;
  bf16* hbuf = (bf16*)(ws + off);   off += (size_t)NP * ID * 2;

  // 4 launches total (was 7): prep fuses gate + both weight transposes + out-zeroing;
  // ffn2 fuses the combine via fp32 atomics.
  prep_kernel<<<G_GATE + G_TR1 + G_TR2, 256, 0, stream>>>(
      x, wg, bg, w1, w2, gate_out, out, xb, pair_w, tokexp, w1t, w2t);
  route_kernel<<<NE, 256, 0, stream>>>(tokexp, elist, counts);
  // ffn1: 256x256 tiles, 1-D grid, bijective XCD chunk swizzle (n-fast in chunk)
  ffn1_kernel<<<FFN1_GRID, 512, 0, stream>>>(xb, w1t, b1, counts, elist, hbuf);
  // ffn2: XCD-pinned (grid.x = 8 = XCD id under %8 round-robin)
  ffn2_kernel<<<dim3(8, SLOTS), 512, 0, stream>>>(hbuf, w2t, b2, counts, elist, pair_w, out);
}

// Round 8
// 323.629 us; speedup vs baseline: 1.4369x; 1.4369x over previous
//
#include <hip/hip_runtime.h>
#include <hip/hip_bf16.h>
#include <cmath>

#define NT 4096      // B*S tokens
#define HD 768
#define ID 3072
#define NE 7
#define NP 8192      // NT * TOP_K
#define TM 256
#define TN 256
#define BK 32        // 4 chunks of 8 bf16 per row per K-tile
#define KS 2         // split-K factor for ffn2
#define NT2 (HD / TN)   // 3 n-tiles in ffn2
#define SLOTS 102    // worst-case tiles per XCD in ffn2 ((32+2)*3)
#define NRING 4      // LDS ring depth (stage 3 tiles ahead)
#define FFN1_MT 39   // worst-case sum of ceil(cnt/256) = 32 + 7
#define FFN1_NT (ID / TN)          // 12 n-tiles
#define FFN1_GRID (FFN1_NT * FFN1_MT)   // 468

// prep_kernel grid sections
#define G_GATE 1024              // 4 tokens (1 per wave) per 256-thread block
#define G_TR1  (48 * 12 * NE)    // w1 transpose tiles (N=ID/64 x K=HD/64 x E)
#define G_TR2  (12 * 48 * NE)    // w2 transpose tiles (N=HD/64 x K=ID/64 x E)

using short8 = __attribute__((ext_vector_type(8))) short;
using f32x4  = __attribute__((ext_vector_type(4))) float;
typedef __hip_bfloat16 bf16;

// async global->LDS, 16B per lane, wave-uniform base + lane*16
typedef const __attribute__((address_space(1))) void* gas_ptr;
typedef __attribute__((address_space(3))) void* las_ptr;
#define GLDS(g, l) __builtin_amdgcn_global_load_lds((gas_ptr)(g), (las_ptr)(l), 16, 0, 0)

#define BAR()   asm volatile("s_barrier" ::: "memory")
#define WAITL() asm volatile("s_waitcnt lgkmcnt(0)" ::: "memory")
#define WV8()   asm volatile("s_waitcnt vmcnt(8)" ::: "memory")
#define WV4()   asm volatile("s_waitcnt vmcnt(4)" ::: "memory")
#define WV0()   asm volatile("s_waitcnt vmcnt(0)" ::: "memory")
#define SCHEDB() __builtin_amdgcn_sched_barrier(0)

__device__ inline float b2f(unsigned short u) {
  unsigned v = (unsigned)u << 16; float f; __builtin_memcpy(&f, &v, 4); return f;
}

// exact-erf GELU via A&S 7.1.26 rational (|err| <= 1.5e-7, branch-free, v_exp/v_rcp)
__device__ inline float gelu_erf(float v) {
  float xa = fabsf(v) * 0.70710678118654752f;
  float t  = __builtin_amdgcn_rcpf(1.0f + 0.3275911f * xa);
  float p  = t * (0.254829592f + t * (-0.284496736f + t * (1.421413741f +
             t * (-1.453152027f + t * 1.061405429f))));
  float er = 1.0f - p * __expf(-xa * xa);
  er = (v < 0.0f) ? -er : er;
  return 0.5f * v * (1.0f + er);
}

// ---------------- fp32 [K][N] -> bf16 [N][K] 64x64 transpose tile (shared body) ----------
__device__ inline void transpose_body(const float* __restrict__ s, bf16* __restrict__ d,
                                      int K, int N, int n0, int k0, int t,
                                      float (*tile)[65]) {
  {
    int kk = t >> 4;            // 0..15
    int nc = (t & 15) << 2;     // 0,4,...,60
#pragma unroll
    for (int r = 0; r < 4; r++) {
      int k = kk + r * 16;
      float4 v = *(const float4*)(s + (size_t)(k0 + k) * N + n0 + nc);
      tile[k][nc + 0] = v.x; tile[k][nc + 1] = v.y;
      tile[k][nc + 2] = v.z; tile[k][nc + 3] = v.w;
    }
  }
  __syncthreads();
  {
    int c = t & 15;             // k-chunk (4 elems)
    int nbase = t >> 4;         // 0..15
#pragma unroll
    for (int r = 0; r < 4; r++) {
      int n = nbase + r * 16;
      bf16 tmp[4];
#pragma unroll
      for (int i = 0; i < 4; i++) tmp[i] = __float2bfloat16(tile[4 * c + i][n]);
      ushort4 u; __builtin_memcpy(&u, tmp, 8);
      *(ushort4*)(d + (size_t)(n0 + n) * K + k0 + 4 * c) = u;
    }
  }
}

// ---------------- prep: gate (+x->bf16) || w1 transpose || w2 transpose ----------------
// Sections by blockIdx.x; fully data-independent -> one launch replaces three and the
// three memory streams overlap instead of serializing across launch gaps.
__global__ __launch_bounds__(256) void prep_kernel(
    const float* __restrict__ x, const float* __restrict__ wg, const float* __restrict__ bg,
    const float* __restrict__ w1, const float* __restrict__ w2,
    float* __restrict__ gate_out, bf16* __restrict__ xb,
    float* __restrict__ pair_w, int* __restrict__ tokexp,
    bf16* __restrict__ w1t, bf16* __restrict__ w2t)
{
  __shared__ float tile[64][65];
  int b = blockIdx.x;
  int tid = threadIdx.x;

  if (b < G_GATE) {
    // ---- gate section: 4 tokens per block, one per wave ----
    int wavei = tid >> 6, lane = tid & 63;
    int t = b * 4 + wavei;
    const float* xr = x + (size_t)t * HD;
    float acc[NE];
#pragma unroll
    for (int e = 0; e < NE; e++) acc[e] = 0.f;
#pragma unroll
    for (int j = 0; j < HD / 64; j++) {
      int h = lane + j * 64;
      float xv = xr[h];
      xb[(size_t)t * HD + h] = __float2bfloat16(xv);
      const float* wr = wg + (size_t)h * NE;
#pragma unroll
      for (int e = 0; e < NE; e++) acc[e] += xv * wr[e];
    }
#pragma unroll
    for (int e = 0; e < NE; e++) {
      float v = acc[e];
      for (int s = 32; s > 0; s >>= 1) v += __shfl_down(v, s, 64);
      acc[e] = v;
    }
    if (lane == 0) {
      float lg[NE];
#pragma unroll
      for (int e = 0; e < NE; e++) lg[e] = acc[e] + bg[e];
      int i0 = 0;
      for (int e = 1; e < NE; e++) if (lg[e] > lg[i0]) i0 = e;  // first index wins ties
      int i1 = -1;
      for (int e = 0; e < NE; e++) {
        if (e == i0) continue;
        if (i1 < 0 || lg[e] > lg[i1]) i1 = e;
      }
      float v0 = lg[i0], v1 = lg[i1];
      float e1 = expf(v1 - v0);
      float inv = 1.f / (1.f + e1);
      float w0 = inv, w1v = e1 * inv;
      float* go = gate_out + (size_t)t * NE;
#pragma unroll
      for (int e = 0; e < NE; e++) go[e] = 0.f;
      go[i0] = w0; go[i1] = w1v;
      pair_w[2 * t + 0] = w0;
      pair_w[2 * t + 1] = w1v;
      tokexp[2 * t + 0] = i0;
      tokexp[2 * t + 1] = i1;
    }
  } else if (b < G_GATE + G_TR1) {
    // ---- w1 transpose: [HD][ID] fp32 -> [ID][HD] bf16 per expert ----
    int id = b - G_GATE;
    int e = id / (48 * 12);
    int rem = id % (48 * 12);
    int bx = rem % 48, by = rem / 48;        // bx: n-tile (ID), by: k-tile (HD)
    transpose_body(w1 + (size_t)e * HD * ID, w1t + (size_t)e * HD * ID,
                   HD, ID, bx * 64, by * 64, tid, tile);
  } else {
    // ---- w2 transpose: [ID][HD] fp32 -> [HD][ID] bf16 per expert ----
    int id = b - G_GATE - G_TR1;
    int e = id / (12 * 48);
    int rem = id % (12 * 48);
    int bx = rem % 12, by = rem / 12;        // bx: n-tile (HD), by: k-tile (ID)
    transpose_body(w2 + (size_t)e * ID * HD, w2t + (size_t)e * ID * HD,
                   ID, HD, bx * 64, by * 64, tid, tile);
  }
}

// ---------------- routing: deterministic compaction, one block per expert ----------------
__global__ __launch_bounds__(256) void route_kernel(
    const int* __restrict__ tokexp, int* __restrict__ elist, int* __restrict__ counts)
{
  __shared__ int wcnt[4];
  int e = blockIdx.x;
  int tid = threadIdx.x, wv = tid >> 6, ln = tid & 63;
  int base = 0;
  for (int chunk = 0; chunk < NP; chunk += 256) {
    int p = chunk + tid;
    bool m = (tokexp[p] == e);
    unsigned long long bal = __ballot(m);
    if (ln == 0) wcnt[wv] = __popcll(bal);
    __syncthreads();
    int pre = 0;
#pragma unroll
    for (int w = 0; w < 4; w++) pre += (w < wv) ? wcnt[w] : 0;
    int rank = pre + __popcll(bal & ((1ull << ln) - 1ull));
    if (m) elist[e * NP + base + rank] = p;
    base += wcnt[0] + wcnt[1] + wcnt[2] + wcnt[3];
    __syncthreads();
  }
  if (tid == 0) counts[e] = base;
}

// ================= shared GEMM machinery (R4 schedule — best measured) =================
// 256x256 tile, 512 threads = 8 waves (2m x 4n), per-wave output 128x64, acc[8][4].
// LDS: ring of 4 K-tiles (BK=32): As/Bs[4][256][4][8] = 128 KB + plist -> 1 block/CU.
// Chunk-XOR layout (0 conflicts): phys slot p holds logical chunk kc = p ^ ((row>>1)&3);
// fragment read phys ph = quad ^ ((lr>>1)&3). Staging c0=tid (rows 0..127), c1=tid+512.
// Two phases per K-tile, 2 barriers each; counted vmcnt (8/4/0 tail) keeps 2-3 tiles
// in flight across barriers. MFMA operands SWAPPED (bfr, af) -> lane holds 4
// consecutive output cols -> 8 B vectorized epilogue stores.

// ---------------- grouped GEMM 1: h = gelu(x_g @ W1e + b1e), bf16 out ----------------
// Bijective XCD swizzle: nwg=468, q=58, r=4; xcd = raw%8 gets a contiguous n-fast run.
__global__ __launch_bounds__(512, 2) void ffn1_kernel(
    const bf16* __restrict__ xb, const bf16* __restrict__ w1t, const float* __restrict__ b1,
    const int* __restrict__ counts, const int* __restrict__ elist, bf16* __restrict__ hbuf)
{
  __shared__ bf16 As[NRING][TM][4][8];   // 64 KB
  __shared__ bf16 Bs[NRING][TN][4][8];   // 64 KB
  __shared__ int plist[TM];

  int tid = threadIdx.x;
  int raw = blockIdx.x;
  int xcd = raw & 7, pos = raw >> 3;
  int v = (xcd < 4) ? xcd * 59 + pos : 236 + (xcd - 4) * 58 + pos;
  int by = v / FFN1_NT, bx = v % FFN1_NT;

  int e, base = 0, cnt = 0, acct = 0;
  bool found = false;
  for (e = 0; e < NE; e++) {
    cnt = counts[e];
    int tiles = (cnt + TM - 1) / TM;
    if (by < acct + tiles) { base = (by - acct) * TM; found = true; break; }
    acct += tiles;
  }
  if (!found) return;

  if (tid < TM) {
    int r = base + tid;
    plist[tid] = (r < cnt) ? elist[e * NP + r] : -1;
  }
  __syncthreads();

  const int n0 = bx * TN;
  const bf16* Bsrc = w1t + (size_t)e * ID * HD;  // [ID][HD] bf16, K-contiguous

  int c0 = tid, c1 = tid + 512;
  int r0 = c0 >> 2, k0 = (c0 & 3) ^ ((r0 >> 1) & 3);
  int r1 = c1 >> 2, k1 = (c1 & 3) ^ ((r1 >> 1) & 3);
  int pr0 = plist[r0], pr1 = plist[r1];
  const bf16* a0 = xb + (size_t)((pr0 >= 0 ? pr0 : 0) >> 1) * HD + k0 * 8;
  const bf16* a1 = xb + (size_t)((pr1 >= 0 ? pr1 : 0) >> 1) * HD + k1 * 8;
  const bf16* b0 = Bsrc + (size_t)(n0 + r0) * HD + k0 * 8;
  const bf16* b1v = Bsrc + (size_t)(n0 + r1) * HD + k1 * 8;

#define STAGE_A(t_) do { bf16* d_ = (bf16*)As + (size_t)((t_) & 3) * TM * 32;    \
    GLDS(a0 + (size_t)(t_) * BK, d_ + c0 * 8);                                   \
    GLDS(a1 + (size_t)(t_) * BK, d_ + c1 * 8); } while (0)
#define STAGE_B(t_) do { bf16* d_ = (bf16*)Bs + (size_t)((t_) & 3) * TN * 32;    \
    GLDS(b0 + (size_t)(t_) * BK, d_ + c0 * 8);                                   \
    GLDS(b1v + (size_t)(t_) * BK, d_ + c1 * 8); } while (0)

  int wave = tid >> 6, lane = tid & 63;
  int wm = (wave >> 2) * 128, wn = (wave & 3) * 64;
  int lr = lane & 15, quad = lane >> 4;
  int ph = quad ^ ((lr >> 1) & 3);

  f32x4 acc[8][4] = {};
  const int NIT = HD / BK;  // 24

  STAGE_A(0); STAGE_B(0);
  STAGE_A(1); STAGE_B(1);
  STAGE_A(2); STAGE_B(2);
  WV8(); BAR();

  for (int t = 0; t < NIT; ++t) {
    int q = t & 3;
    short8 af[4], bfr[4];
    // ---- phase A: rows wm+0..63 ----
#pragma unroll
    for (int mi = 0; mi < 4; mi++) af[mi] = *(const short8*)&As[q][wm + mi * 16 + lr][ph][0];
#pragma unroll
    for (int nj = 0; nj < 4; nj++) bfr[nj] = *(const short8*)&Bs[q][wn + nj * 16 + lr][ph][0];
    if (t + 3 < NIT) STAGE_A(t + 3);
    BAR();
    WAITL(); SCHEDB();
    __builtin_amdgcn_s_setprio(1);
#pragma unroll
    for (int mi = 0; mi < 4; mi++)
#pragma unroll
      for (int nj = 0; nj < 4; nj++)
        acc[mi][nj] = __builtin_amdgcn_mfma_f32_16x16x32_bf16(bfr[nj], af[mi], acc[mi][nj], 0, 0, 0);
    __builtin_amdgcn_s_setprio(0);
    BAR();
    // ---- phase B: rows wm+64..127 ----
#pragma unroll
    for (int mi = 0; mi < 4; mi++) af[mi] = *(const short8*)&As[q][wm + 64 + mi * 16 + lr][ph][0];
    if (t + 3 < NIT) STAGE_B(t + 3);
    if (t + 3 < NIT) { WV8(); } else if (t + 2 < NIT) { WV4(); } else if (t + 1 < NIT) { WV0(); }
    BAR();
    WAITL(); SCHEDB();
    __builtin_amdgcn_s_setprio(1);
#pragma unroll
    for (int mi = 0; mi < 4; mi++)
#pragma unroll
      for (int nj = 0; nj < 4; nj++)
        acc[4 + mi][nj] = __builtin_amdgcn_mfma_f32_16x16x32_bf16(bfr[nj], af[mi], acc[4 + mi][nj], 0, 0, 0);
    __builtin_amdgcn_s_setprio(0);
    BAR();
  }
#undef STAGE_A
#undef STAGE_B

  // epilogue: lane holds 4 consecutive cols (n = n0+wn+nj*16+quad*4+r) of row
  // m = wm+mi*16+lr -> 8 B stores; nj inner completes each 128 B line fast.
  const float* b1e = b1 + (size_t)e * ID;
#pragma unroll
  for (int mi = 0; mi < 8; mi++) {
    int mrow = wm + mi * 16 + lr;
    int p = plist[mrow];
    if (p >= 0) {
      bf16* drow = hbuf + (size_t)p * ID;
#pragma unroll
      for (int nj = 0; nj < 4; nj++) {
        int colb = n0 + wn + nj * 16 + (quad << 2);
        float4 bs = *(const float4*)(b1e + colb);
        bf16 o[4];
        o[0] = __float2bfloat16(gelu_erf(acc[mi][nj][0] + bs.x));
        o[1] = __float2bfloat16(gelu_erf(acc[mi][nj][1] + bs.y));
        o[2] = __float2bfloat16(gelu_erf(acc[mi][nj][2] + bs.z));
        o[3] = __float2bfloat16(gelu_erf(acc[mi][nj][3] + bs.w));
        ushort4 u; __builtin_memcpy(&u, o, 8);
        *(ushort4*)(drow + colb) = u;
      }
    }
  }
}

// ---------------- grouped GEMM 2 (split-K, XCD-pinned): pout[seg] = (h @ W2e[kseg] [+b2e]) * gate_w
// grid = (8, SLOTS): blockIdx.x == linear%8 == XCD. Pair p=2e+seg pinned to XCD p%8 so
// its B-half-panel (2.36 MB, L2-fits) stays resident; n varies fastest within a pair.
__global__ __launch_bounds__(512, 2) void ffn2_kernel(
    const bf16* __restrict__ hbuf, const bf16* __restrict__ w2t, const float* __restrict__ b2,
    const int* __restrict__ counts, const int* __restrict__ elist,
    const float* __restrict__ pair_w, bf16* __restrict__ pout)
{
  __shared__ bf16 As[NRING][TM][4][8];
  __shared__ bf16 Bs[NRING][TN][4][8];
  __shared__ int plist[TM];

  int tid = threadIdx.x;
  int xcd = blockIdx.x;
  int slot = blockIdx.y;
  int e = 0, seg = 0, base = 0, cnt = 0, n0 = 0;
  bool found = false;
  for (int p = xcd; p < 2 * NE; p += 8) {
    int pe = p >> 1;
    int c = counts[pe];
    int tiles = ((c + TM - 1) / TM) * NT2;
    if (slot < tiles) {
      e = pe; seg = p & 1; cnt = c;
      base = (slot / NT2) * TM;
      n0 = (slot % NT2) * TN;
      found = true; break;
    }
    slot -= tiles;
  }
  if (!found) return;

  if (tid < TM) {
    int r = base + tid;
    plist[tid] = (r < cnt) ? elist[e * NP + r] : -1;
  }
  __syncthreads();

  const int kbase = seg * (ID / KS);
  const bf16* Bsrc = w2t + (size_t)e * HD * ID;  // [HD][ID] bf16, K-contiguous

  int c0 = tid, c1 = tid + 512;
  int r0 = c0 >> 2, k0 = (c0 & 3) ^ ((r0 >> 1) & 3);
  int r1 = c1 >> 2, k1 = (c1 & 3) ^ ((r1 >> 1) & 3);
  int pr0 = plist[r0], pr1 = plist[r1];
  const bf16* a0 = hbuf + (size_t)(pr0 >= 0 ? pr0 : 0) * ID + kbase + k0 * 8;
  const bf16* a1 = hbuf + (size_t)(pr1 >= 0 ? pr1 : 0) * ID + kbase + k1 * 8;
  const bf16* b0 = Bsrc + (size_t)(n0 + r0) * ID + kbase + k0 * 8;
  const bf16* b1v = Bsrc + (size_t)(n0 + r1) * ID + kbase + k1 * 8;

#define STAGE_A(t_) do { bf16* d_ = (bf16*)As + (size_t)((t_) & 3) * TM * 32;    \
    GLDS(a0 + (size_t)(t_) * BK, d_ + c0 * 8);                                   \
    GLDS(a1 + (size_t)(t_) * BK, d_ + c1 * 8); } while (0)
#define STAGE_B(t_) do { bf16* d_ = (bf16*)Bs + (size_t)((t_) & 3) * TN * 32;    \
    GLDS(b0 + (size_t)(t_) * BK, d_ + c0 * 8);                                   \
    GLDS(b1v + (size_t)(t_) * BK, d_ + c1 * 8); } while (0)

  int wave = tid >> 6, lane = tid & 63;
  int wm = (wave >> 2) * 128, wn = (wave & 3) * 64;
  int lr = lane & 15, quad = lane >> 4;
  int ph = quad ^ ((lr >> 1) & 3);

  f32x4 acc[8][4] = {};
  const int NIT = (ID / KS) / BK;  // 48

  STAGE_A(0); STAGE_B(0);
  STAGE_A(1); STAGE_B(1);
  STAGE_A(2); STAGE_B(2);
  WV8(); BAR();

  for (int t = 0; t < NIT; ++t) {
    int q = t & 3;
    short8 af[4], bfr[4];
    // ---- phase A ----
#pragma unroll
    for (int mi = 0; mi < 4; mi++) af[mi] = *(const short8*)&As[q][wm + mi * 16 + lr][ph][0];
#pragma unroll
    for (int nj = 0; nj < 4; nj++) bfr[nj] = *(const short8*)&Bs[q][wn + nj * 16 + lr][ph][0];
    if (t + 3 < NIT) STAGE_A(t + 3);
    BAR();
    WAITL(); SCHEDB();
    __builtin_amdgcn_s_setprio(1);
#pragma unroll
    for (int mi = 0; mi < 4; mi++)
#pragma unroll
      for (int nj = 0; nj < 4; nj++)
        acc[mi][nj] = __builtin_amdgcn_mfma_f32_16x16x32_bf16(bfr[nj], af[mi], acc[mi][nj], 0, 0, 0);
    __builtin_amdgcn_s_setprio(0);
    BAR();
    // ---- phase B ----
#pragma unroll
    for (int mi = 0; mi < 4; mi++) af[mi] = *(const short8*)&As[q][wm + 64 + mi * 16 + lr][ph][0];
    if (t + 3 < NIT) STAGE_B(t + 3);
    if (t + 3 < NIT) { WV8(); } else if (t + 2 < NIT) { WV4(); } else if (t + 1 < NIT) { WV0(); }
    BAR();
    WAITL(); SCHEDB();
    __builtin_amdgcn_s_setprio(1);
#pragma unroll
    for (int mi = 0; mi < 4; mi++)
#pragma unroll
      for (int nj = 0; nj < 4; nj++)
        acc[4 + mi][nj] = __builtin_amdgcn_mfma_f32_16x16x32_bf16(bfr[nj], af[mi], acc[4 + mi][nj], 0, 0, 0);
    __builtin_amdgcn_s_setprio(0);
    BAR();
  }
#undef STAGE_A
#undef STAGE_B

  const float* b2e = b2 + (size_t)e * HD;
#pragma unroll
  for (int mi = 0; mi < 8; mi++) {
    int mrow = wm + mi * 16 + lr;
    int p = plist[mrow];
    if (p >= 0) {
      float pw = pair_w[p];
      bf16* drow = pout + ((size_t)seg * NP + p) * HD;
#pragma unroll
      for (int nj = 0; nj < 4; nj++) {
        int colb = n0 + wn + nj * 16 + (quad << 2);
        float bx_ = 0.f, by_ = 0.f, bz_ = 0.f, bw_ = 0.f;
        if (seg == 0) {
          float4 bs = *(const float4*)(b2e + colb);
          bx_ = bs.x; by_ = bs.y; bz_ = bs.z; bw_ = bs.w;
        }
        bf16 o[4];
        o[0] = __float2bfloat16((acc[mi][nj][0] + bx_) * pw);
        o[1] = __float2bfloat16((acc[mi][nj][1] + by_) * pw);
        o[2] = __float2bfloat16((acc[mi][nj][2] + bz_) * pw);
        o[3] = __float2bfloat16((acc[mi][nj][3] + bw_) * pw);
        ushort4 u; __builtin_memcpy(&u, o, 8);
        *(ushort4*)(drow + colb) = u;
      }
    }
  }
}

// ---------------- combine: out[t] = sum over 2 experts x KS k-segments ----------------
__global__ __launch_bounds__(192) void combine_kernel(
    const bf16* __restrict__ pout, float* __restrict__ out)
{
  int t = blockIdx.x, j = threadIdx.x;  // 192 threads = 768/4
  f32x4 o = {0.f, 0.f, 0.f, 0.f};
#pragma unroll
  for (int s = 0; s < KS; s++) {
#pragma unroll
    for (int k = 0; k < 2; k++) {
      const ushort4* v = (const ushort4*)(pout + ((size_t)s * NP + 2 * t + k) * HD);
      ushort4 u = v[j];
      o[0] += b2f(u.x); o[1] += b2f(u.y); o[2] += b2f(u.z); o[3] += b2f(u.w);
    }
  }
  ((f32x4*)(out + (size_t)t * HD))[j] = o;
}

extern "C" void kernel_launch(void* const* d_in, const int* in_sizes, int n_in,
                              void* d_out, int out_size, void* d_ws, size_t ws_size,
                              hipStream_t stream)
{
  const float* x  = (const float*)d_in[0];
  const float* wg = (const float*)d_in[1];
  const float* bg = (const float*)d_in[2];
  const float* w1 = (const float*)d_in[3];
  const float* b1 = (const float*)d_in[4];
  const float* w2 = (const float*)d_in[5];
  const float* b2 = (const float*)d_in[6];
  float* out = (float*)d_out;
  float* gate_out = out + (size_t)NT * HD;  // second output [B,S,E]

  // workspace layout (~141 MB total, 16B-aligned offsets)
  char* ws = (char*)d_ws;
  size_t off = 0;
  int* counts  = (int*)(ws + off);  off += 256;
  int* tokexp  = (int*)(ws + off);  off += (size_t)NP * 4;
  int* elist   = (int*)(ws + off);  off += (size_t)NE * NP * 4;
  float* pair_w = (float*)(ws + off); off += (size_t)NP * 4;
  bf16* xb   = (bf16*)(ws + off);   off += (size_t)NT * HD * 2;
  bf16* w1t  = (bf16*)(ws + off);   off += (size_t)NE * HD * ID * 2;
  bf16* w2t  = (bf16*)(ws + off);   off += (size_t)NE * HD * ID * 2;
  bf16* hbuf = (bf16*)(ws + off);   off += (size_t)NP * ID * 2;
  bf16* pout = (bf16*)(ws + off);   off += (size_t)KS * NP * HD * 2;

  // 5 launches (was 7): prep fuses gate + both weight transposes.
  prep_kernel<<<G_GATE + G_TR1 + G_TR2, 256, 0, stream>>>(
      x, wg, bg, w1, w2, gate_out, xb, pair_w, tokexp, w1t, w2t);
  route_kernel<<<NE, 256, 0, stream>>>(tokexp, elist, counts);
  // ffn1: 256x256 tiles, 1-D grid, bijective XCD chunk swizzle (n-fast in chunk)
  ffn1_kernel<<<FFN1_GRID, 512, 0, stream>>>(xb, w1t, b1, counts, elist, hbuf);
  // ffn2: XCD-pinned (grid.x = 8 = XCD id under %8 round-robin)
  ffn2_kernel<<<dim3(8, SLOTS), 512, 0, stream>>>(hbuf, w2t, b2, counts, elist, pair_w, pout);
  combine_kernel<<<NT, 192, 0, stream>>>(pout, out);
}